// Round 1
// baseline (105.135 us; speedup 1.0000x reference)
//
#include <hip/hip_runtime.h>

// SmoothingModule: s[t] = q[t]*s[t-1] + pe[t]*z[t]  (per b,d), out masked by t < lengths[b].
// 3-kernel chunked scan: CHUNK=16 rows/chunk.
//  k_local: per (b,c) chunk-local scan end S[b,c,d] (vector) and A[b,c] = prod q (scalar).
//  k_carry: parallel Hillis-Steele scan over chunks (affine maps) -> Carry[b,c,d] = state entering chunk c.
//  k_apply: s = Carry; continue serial scan over 16 rows; mask + store.
// float4 everywhere (D % 4 == 0). Chunks with t0 >= lengths[b] are fully masked:
// skip z reads entirely (their S/A only influence other masked chunks).

#define CHUNK 16
#define NCMAX 512  // supports T up to 8192

__global__ __launch_bounds__(128) void k_local(
    const float* __restrict__ z, const float* __restrict__ P,
    const int* __restrict__ lengths,
    float* __restrict__ S, float* __restrict__ A,
    int B, int T, int D, int NC) {
  int blk = blockIdx.x;
  int b = blk / NC, c = blk % NC;
  int t0 = c * CHUNK;
  int tid = threadIdx.x;
  int D4 = D >> 2;
  float4* S4 = (float4*)(S + ((size_t)b * NC + c) * D);
  int L = lengths[b];
  if (t0 >= L) {
    // fully masked chunk: S/A only feed later (also masked) chunks. Identity map.
    float4 zero = make_float4(0.f, 0.f, 0.f, 0.f);
    for (int d4 = tid; d4 < D4; d4 += blockDim.x) S4[d4] = zero;
    if (tid == 0) A[b * NC + c] = 1.0f;
    return;
  }
  __shared__ float p_s[CHUNK], q_s[CHUNK];
  if (tid < CHUNK) {
    int tg = t0 + tid;
    float p = (tg < T) ? P[(size_t)b * T + tg] : 0.0f;
    p = fminf(fmaxf(p, 0.0f), 1.0f - 1e-6f);
    q_s[tid] = 1.0f - p;
    p_s[tid] = fmaxf(p, 1e-6f);
  }
  __syncthreads();
  int nt = min(CHUNK, T - t0);
  const float4* z4 = (const float4*)(z + ((size_t)b * T + t0) * D);
  for (int d4 = tid; d4 < D4; d4 += blockDim.x) {
    float4 s = make_float4(0.f, 0.f, 0.f, 0.f);
#pragma unroll
    for (int t = 0; t < CHUNK; ++t) {
      if (t < nt) {
        float4 zv = z4[(size_t)t * D4 + d4];
        float q = q_s[t], pe = p_s[t];
        s.x = fmaf(q, s.x, pe * zv.x);
        s.y = fmaf(q, s.y, pe * zv.y);
        s.z = fmaf(q, s.z, pe * zv.z);
        s.w = fmaf(q, s.w, pe * zv.w);
      }
    }
    S4[d4] = s;
  }
  if (tid == 0) {
    float r = 1.0f;
    for (int t = 0; t < nt; ++t) r *= q_s[t];
    A[b * NC + c] = r;
  }
}

// grid: B * D4 blocks, blockDim = NC (<= NCMAX). Thread c scans chunk axis.
__global__ void k_carry(
    const float* __restrict__ S, const float* __restrict__ A,
    float* __restrict__ Carry, int D4, int NC) {
  int b = blockIdx.x / D4;
  int d4 = blockIdx.x % D4;
  int c = threadIdx.x;
  __shared__ float sh_a[NCMAX];
  __shared__ float4 sh_v[NCMAX];
  float a = A[b * NC + c];
  const float4* S4 = (const float4*)S;
  float4 sv = S4[((size_t)b * NC + c) * D4 + d4];
  sh_a[c] = a;
  sh_v[c] = sv;
  __syncthreads();
  // inclusive scan of affine maps x -> a*x + sv, composed left-to-right over c
  for (int off = 1; off < NC; off <<= 1) {
    float ap = 1.0f;
    float4 vp = make_float4(0.f, 0.f, 0.f, 0.f);
    bool has = (c >= off);
    if (has) { ap = sh_a[c - off]; vp = sh_v[c - off]; }
    __syncthreads();
    if (has) {
      sv.x = fmaf(a, vp.x, sv.x);
      sv.y = fmaf(a, vp.y, sv.y);
      sv.z = fmaf(a, vp.z, sv.z);
      sv.w = fmaf(a, vp.w, sv.w);
      a *= ap;
      sh_a[c] = a;
      sh_v[c] = sv;
    }
    __syncthreads();
  }
  float4 car = make_float4(0.f, 0.f, 0.f, 0.f);
  if (c > 0) car = sh_v[c - 1];  // exclusive prefix = state entering chunk c
  float4* C4 = (float4*)Carry;
  C4[((size_t)b * NC + c) * D4 + d4] = car;
}

__global__ __launch_bounds__(128) void k_apply(
    const float* __restrict__ z, const float* __restrict__ P,
    const float* __restrict__ Carry, const int* __restrict__ lengths,
    float* __restrict__ out,
    int B, int T, int D, int NC) {
  int blk = blockIdx.x;
  int b = blk / NC, c = blk % NC;
  int t0 = c * CHUNK;
  int tid = threadIdx.x;
  int D4 = D >> 2;
  int nt = min(CHUNK, T - t0);
  float4* o4 = (float4*)(out + ((size_t)b * T + t0) * D);
  int L = lengths[b];
  if (t0 >= L) {
    float4 zero = make_float4(0.f, 0.f, 0.f, 0.f);
    for (int t = 0; t < nt; ++t)
      for (int d4 = tid; d4 < D4; d4 += blockDim.x)
        o4[(size_t)t * D4 + d4] = zero;
    return;
  }
  __shared__ float p_s[CHUNK], q_s[CHUNK];
  if (tid < CHUNK) {
    int tg = t0 + tid;
    float p = (tg < T) ? P[(size_t)b * T + tg] : 0.0f;
    p = fminf(fmaxf(p, 0.0f), 1.0f - 1e-6f);
    q_s[tid] = 1.0f - p;
    p_s[tid] = fmaxf(p, 1e-6f);
  }
  __syncthreads();
  const float4* z4 = (const float4*)(z + ((size_t)b * T + t0) * D);
  const float4* C4 = (const float4*)(Carry + ((size_t)b * NC + c) * D);
  for (int d4 = tid; d4 < D4; d4 += blockDim.x) {
    float4 s = C4[d4];
#pragma unroll
    for (int t = 0; t < CHUNK; ++t) {
      if (t < nt) {
        float4 zv = z4[(size_t)t * D4 + d4];
        float q = q_s[t], pe = p_s[t];
        s.x = fmaf(q, s.x, pe * zv.x);
        s.y = fmaf(q, s.y, pe * zv.y);
        s.z = fmaf(q, s.z, pe * zv.z);
        s.w = fmaf(q, s.w, pe * zv.w);
        float4 o = ((t0 + t) < L) ? s : make_float4(0.f, 0.f, 0.f, 0.f);
        o4[(size_t)t * D4 + d4] = o;
      }
    }
  }
}

extern "C" void kernel_launch(void* const* d_in, const int* in_sizes, int n_in,
                              void* d_out, int out_size, void* d_ws, size_t ws_size,
                              hipStream_t stream) {
  const float* z = (const float*)d_in[0];
  const float* P = (const float*)d_in[1];
  const int* lengths = (const int*)d_in[2];
  float* out = (float*)d_out;

  int B = in_sizes[2];
  int T = in_sizes[1] / B;
  int D = in_sizes[0] / in_sizes[1];
  int NC = (T + CHUNK - 1) / CHUNK;  // 256 for T=4096
  int D4 = D >> 2;

  // workspace: S [B*NC*D] | A [B*NC] (padded to 4) | Carry [B*NC*D]
  float* S = (float*)d_ws;
  float* A = S + (size_t)B * NC * D;
  float* Carry = A + (((size_t)B * NC + 3) & ~(size_t)3);

  k_local<<<dim3(B * NC), dim3(128), 0, stream>>>(z, P, lengths, S, A, B, T, D, NC);
  k_carry<<<dim3(B * D4), dim3(NC), 0, stream>>>(S, A, Carry, D4, NC);
  k_apply<<<dim3(B * NC), dim3(128), 0, stream>>>(z, P, Carry, lengths, out, B, T, D, NC);
}